// Round 1
// baseline (414.516 us; speedup 1.0000x reference)
//
#include <hip/hip_runtime.h>

// Problem constants (fixed by the reference)
#define BATCH   64
#define NNODE   1024
#define NEDGE   16384
#define ZHDIM   128
#define EFDIM   64
#define MAXZV   13
#define MAXEFV  8

// emb1: out[b,n,c] = z_tables[0][z[b,n,0]][c] + sum_{i=2..6} z_tables[i][z[b,n,i]][c]
// 32 threads per node, each handles a float4 (4 channels). Block 256 = 8 nodes.
__global__ __launch_bounds__(256) void emb1_kernel(
    const int*   __restrict__ z,         // (B,N,8)
    const float* __restrict__ z_tables,  // (8,13,128)
    float*       __restrict__ out)       // (B,N,128)
{
    int tid  = blockIdx.x * 256 + threadIdx.x;
    int node = tid >> 5;          // [0, B*N)
    int c4   = tid & 31;          // float4 group within 128 channels
    if (node >= BATCH * NNODE) return;

    const int* zp = z + node * 8;
    int i0 = zp[0];
    int i2 = zp[2], i3 = zp[3], i4 = zp[4], i5 = zp[5], i6 = zp[6];

    const float4* t = (const float4*)z_tables;  // row stride: 128 floats = 32 float4
    float4 a0 = t[(0 * MAXZV + i0) * 32 + c4];
    float4 a2 = t[(2 * MAXZV + i2) * 32 + c4];
    float4 a3 = t[(3 * MAXZV + i3) * 32 + c4];
    float4 a4 = t[(4 * MAXZV + i4) * 32 + c4];
    float4 a5 = t[(5 * MAXZV + i5) * 32 + c4];
    float4 a6 = t[(6 * MAXZV + i6) * 32 + c4];

    float4 s;
    s.x = a0.x + a2.x + a3.x + a4.x + a5.x + a6.x;
    s.y = a0.y + a2.y + a3.y + a4.y + a5.y + a6.y;
    s.z = a0.z + a2.z + a3.z + a4.z + a5.z + a6.z;
    s.w = a0.w + a2.w + a3.w + a4.w + a5.w + a6.w;

    ((float4*)out)[node * 32 + c4] = s;
}

// ef kernel: 16 threads per edge, each writes one float4 (4 of 64 channels).
__global__ __launch_bounds__(256) void ef_kernel(
    const float* __restrict__ pos,          // (B,N,3)
    const int*   __restrict__ edge_index,   // (B,2,E)
    const int*   __restrict__ edge_features,// (B,E,4)
    const float* __restrict__ center_pos,   // (B,N,3)
    const float* __restrict__ ef_tables,    // (4,8,64)
    const float* __restrict__ dV_table,     // (3,64)
    float*       __restrict__ out)          // (B,E,64)
{
    int tid  = blockIdx.x * 256 + threadIdx.x;
    int edge = tid >> 4;          // [0, B*E)
    int c4   = tid & 15;          // float4 group within 64 channels
    if (edge >= BATCH * NEDGE) return;

    int b = edge >> 14;           // / NEDGE (16384)
    int e = edge & (NEDGE - 1);

    int iu = edge_index[(b * 2 + 0) * NEDGE + e];
    int iv = edge_index[(b * 2 + 1) * NEDGE + e];

    const float* pu = pos + (size_t)(b * NNODE + iu) * 3;
    const float* pv = pos + (size_t)(b * NNODE + iv) * 3;
    float ux = pu[0], uy = pu[1], uz = pu[2];
    float vx = pv[0], vy = pv[1], vz = pv[2];

    float dx = ux - vx, dy = uy - vy, dz = uz - vz;
    float el = sqrtf(fmaxf(dx * dx + dy * dy + dz * dz, 1e-24f));

    // cross(posu, posv) . center_pos[idx_v]
    float cx = uy * vz - uz * vy;
    float cy = uz * vx - ux * vz;
    float cz = ux * vy - uy * vx;
    const float* cp = center_pos + (size_t)(b * NNODE + iv) * 3;
    float dV = cx * cp[0] + cy * cp[1] + cz * cp[2];
    int sgn = (dV > 0.0f) ? 2 : ((dV < 0.0f) ? 0 : 1);  // sign(dV)+1

    // envelope: P=6 -> 1 - 28 x^6 + 48 x^7 - 21 x^8, zero for x >= 1
    float x  = el * 0.1f;                // el / RMAX
    float x2 = x * x;
    float x3 = x2 * x;
    float x6 = x3 * x3;
    float x7 = x6 * x;
    float x8 = x7 * x;
    float env = 1.0f - 28.0f * x6 + 48.0f * x7 - 21.0f * x8;
    env = (x < 1.0f) ? env : 0.0f;

    // edge feature table rows (each 64 floats)
    const int* efp = edge_features + (size_t)edge * 4;
    int f0 = efp[0], f1 = efp[1], f2 = efp[2], f3 = efp[3];
    float4 t0 = ((const float4*)(ef_tables + (size_t)(0 * MAXEFV + f0) * EFDIM))[c4];
    float4 t1 = ((const float4*)(ef_tables + (size_t)(1 * MAXEFV + f1) * EFDIM))[c4];
    float4 t2 = ((const float4*)(ef_tables + (size_t)(2 * MAXEFV + f2) * EFDIM))[c4];
    float4 t3 = ((const float4*)(ef_tables + (size_t)(3 * MAXEFV + f3) * EFDIM))[c4];
    float4 dvt = ((const float4*)(dV_table + (size_t)sgn * EFDIM))[c4];

    const float step  = 10.0f / 63.0f;          // RUP/(EF_DIM-1)
    const float coeff = -0.5f / (step * step);

    float4 res;
    {
        float tsum[4] = {t0.x + t1.x + t2.x + t3.x,
                         t0.y + t1.y + t2.y + t3.y,
                         t0.z + t1.z + t2.z + t3.z,
                         t0.w + t1.w + t2.w + t3.w};
        float dvv[4] = {dvt.x, dvt.y, dvt.z, dvt.w};
        float r[4];
#pragma unroll
        for (int k = 0; k < 4; ++k) {
            int j = c4 * 4 + k;
            float off = step * (float)j;
            float d = el - off;
            float g = expf(coeff * d * d);
            r[k] = (g + tsum[k]) * dvv[k] * env;
        }
        res.x = r[0]; res.y = r[1]; res.z = r[2]; res.w = r[3];
    }

    ((float4*)out)[(size_t)edge * 16 + c4] = res;
}

extern "C" void kernel_launch(void* const* d_in, const int* in_sizes, int n_in,
                              void* d_out, int out_size, void* d_ws, size_t ws_size,
                              hipStream_t stream) {
    const int*   z             = (const int*)  d_in[0];
    const float* pos           = (const float*)d_in[1];
    const int*   edge_index    = (const int*)  d_in[2];
    const int*   edge_features = (const int*)  d_in[3];
    const float* center_pos    = (const float*)d_in[4];
    const float* z_tables      = (const float*)d_in[5];
    const float* ef_tables     = (const float*)d_in[6];
    const float* dV_table      = (const float*)d_in[7];

    float* out_emb1 = (float*)d_out;                                  // B*N*128
    float* out_ef   = out_emb1 + (size_t)BATCH * NNODE * ZHDIM;       // B*E*64

    // emb1: B*N nodes * 32 threads = 2,097,152 threads
    {
        int threads = BATCH * NNODE * 32;
        emb1_kernel<<<threads / 256, 256, 0, stream>>>(z, z_tables, out_emb1);
    }
    // ef: B*E edges * 16 threads = 16,777,216 threads
    {
        int threads = BATCH * NEDGE * 16;
        ef_kernel<<<threads / 256, 256, 0, stream>>>(
            pos, edge_index, edge_features, center_pos, ef_tables, dV_table, out_ef);
    }
}

// Round 2
// 354.730 us; speedup vs baseline: 1.1685x; 1.1685x over previous
//
#include <hip/hip_runtime.h>

// Problem constants (fixed by the reference)
#define BATCH   64
#define NNODE   1024
#define NEDGE   16384
#define ZHDIM   128
#define EFDIM   64
#define MAXZV   13
#define MAXEFV  8
#define NEDGES_TOT (BATCH * NEDGE)        // 1,048,576
#define NCOMBO  4096                      // 8^4 feature combos
#define AROWS   (NCOMBO * 3)              // x3 sign values

// ---------------------------------------------------------------------------
// Workspace layout (d_ws):
//   [0, 3 MB)        : A table, AROWS x 64 floats = 786,432 floats
//   [4 MB, 20 MB)    : per-edge scalars, NEDGES_TOT x float4 {el, env, rowid, sgn}
// ---------------------------------------------------------------------------
#define WS_A_OFF_FLOATS      0
#define WS_SCAL_OFF_FLOATS   (1024 * 1024)   // 4 MB byte offset

// A[row][c] = (sum_i ef_tables[i][f_i][c]) * dV_table[s][c],  row = combo*3 + s
// 16 threads per row (one float4 each). AROWS*16 = 196,608 threads = 768 blocks.
__global__ __launch_bounds__(256) void combine_tables_kernel(
    const float* __restrict__ ef_tables,  // (4,8,64)
    const float* __restrict__ dV_table,   // (3,64)
    float*       __restrict__ A)          // (AROWS,64)
{
    int tid = blockIdx.x * 256 + threadIdx.x;
    int row = tid >> 4;
    int c4  = tid & 15;
    int combo = row / 3;          // compiler emits magic-mul
    int s     = row - combo * 3;
    int f3 = combo & 7, f2 = (combo >> 3) & 7, f1 = (combo >> 6) & 7, f0 = (combo >> 9) & 7;

    const float4* T = (const float4*)ef_tables;   // row stride 64 floats = 16 float4
    float4 t0 = T[(0 * MAXEFV + f0) * 16 + c4];
    float4 t1 = T[(1 * MAXEFV + f1) * 16 + c4];
    float4 t2 = T[(2 * MAXEFV + f2) * 16 + c4];
    float4 t3 = T[(3 * MAXEFV + f3) * 16 + c4];
    float4 dv = ((const float4*)dV_table)[s * 16 + c4];

    float4 o;
    o.x = (t0.x + t1.x + t2.x + t3.x) * dv.x;
    o.y = (t0.y + t1.y + t2.y + t3.y) * dv.y;
    o.z = (t0.z + t1.z + t2.z + t3.z) * dv.z;
    o.w = (t0.w + t1.w + t2.w + t3.w) * dv.w;
    ((float4*)A)[row * 16 + c4] = o;
}

// One thread per edge: compute el, envelope, sign, combined-table row id.
__global__ __launch_bounds__(256) void edge_scalar_kernel(
    const float* __restrict__ pos,           // (B,N,3)
    const int*   __restrict__ edge_index,    // (B,2,E)
    const int*   __restrict__ edge_features, // (B,E,4)
    const float* __restrict__ center_pos,    // (B,N,3)
    float4*      __restrict__ scal)          // (NEDGES_TOT)
{
    int edge = blockIdx.x * 256 + threadIdx.x;   // grid exact: 4096 blocks
    int b = edge >> 14;           // / NEDGE
    int e = edge & (NEDGE - 1);

    int iu = edge_index[(b * 2 + 0) * NEDGE + e];
    int iv = edge_index[(b * 2 + 1) * NEDGE + e];

    const float* pu = pos + (size_t)(b * NNODE + iu) * 3;
    const float* pv = pos + (size_t)(b * NNODE + iv) * 3;
    float ux = pu[0], uy = pu[1], uz = pu[2];
    float vx = pv[0], vy = pv[1], vz = pv[2];

    float dx = ux - vx, dy = uy - vy, dz = uz - vz;
    float el = sqrtf(fmaxf(dx * dx + dy * dy + dz * dz, 1e-24f));

    // cross(posu, posv) . center_pos[idx_v]
    float cx = uy * vz - uz * vy;
    float cy = uz * vx - ux * vz;
    float cz = ux * vy - uy * vx;
    const float* cp = center_pos + (size_t)(b * NNODE + iv) * 3;
    float dV = cx * cp[0] + cy * cp[1] + cz * cp[2];
    int sgn = (dV > 0.0f) ? 2 : ((dV < 0.0f) ? 0 : 1);   // sign(dV)+1

    // envelope: P=6 -> 1 - 28 x^6 + 48 x^7 - 21 x^8, zero for x >= 1
    float x  = el * 0.1f;
    float x3 = x * x * x;
    float x6 = x3 * x3;
    float env = 1.0f - 28.0f * x6 + 48.0f * x6 * x - 21.0f * x6 * x * x;
    env = (x < 1.0f) ? env : 0.0f;

    int4 f = ((const int4*)edge_features)[edge];   // 16B aligned, one dwordx4
    int combo = ((f.x * 8 + f.y) * 8 + f.z) * 8 + f.w;
    int rowid = combo * 3 + sgn;

    float4 o;
    o.x = el;
    o.y = env;
    o.z = __int_as_float(rowid);
    o.w = __int_as_float(sgn);
    scal[edge] = o;
}

// 16 threads per edge, one float4 of the 64 channels each.
// res[c] = (exp(coeff*(el-off_c)^2) * dV[sgn][c] + A[rowid][c]) * env
__global__ __launch_bounds__(256) void ef_expand_kernel(
    const float4* __restrict__ scal,      // (NEDGES_TOT)
    const float*  __restrict__ A,         // (AROWS,64)
    const float*  __restrict__ dV_table,  // (3,64)
    float*        __restrict__ out)       // (B,E,64)
{
    int tid  = blockIdx.x * 256 + threadIdx.x;   // grid exact: 65536 blocks
    int edge = tid >> 4;
    int c4   = tid & 15;

    float4 sc = scal[edge];           // broadcast across the 16-lane group
    float el  = sc.x;
    float env = sc.y;
    int rowid = __float_as_int(sc.z);
    int sgn   = __float_as_int(sc.w);

    float4 a  = ((const float4*)A)[rowid * 16 + c4];
    float4 dv = ((const float4*)dV_table)[sgn * 16 + c4];

    const float step  = 10.0f / 63.0f;
    const float coeff = -0.5f / (step * step);

    float av[4]  = {a.x, a.y, a.z, a.w};
    float dvv[4] = {dv.x, dv.y, dv.z, dv.w};
    float r[4];
#pragma unroll
    for (int k = 0; k < 4; ++k) {
        int j = c4 * 4 + k;
        float d = el - step * (float)j;
        float g = expf(coeff * d * d);
        r[k] = fmaf(g, dvv[k], av[k]) * env;
    }

    float4 res;
    res.x = r[0]; res.y = r[1]; res.z = r[2]; res.w = r[3];
    ((float4*)out)[(size_t)edge * 16 + c4] = res;
}

// emb1: out[b,n,c] = z_tables[0][z[b,n,0]][c] + sum_{i=2..6} z_tables[i][z[b,n,i]][c]
__global__ __launch_bounds__(256) void emb1_kernel(
    const int*   __restrict__ z,         // (B,N,8)
    const float* __restrict__ z_tables,  // (8,13,128)
    float*       __restrict__ out)       // (B,N,128)
{
    int tid  = blockIdx.x * 256 + threadIdx.x;   // grid exact: 8192 blocks
    int node = tid >> 5;
    int c4   = tid & 31;

    const int* zp = z + node * 8;
    int i0 = zp[0];
    int i2 = zp[2], i3 = zp[3], i4 = zp[4], i5 = zp[5], i6 = zp[6];

    const float4* t = (const float4*)z_tables;   // row stride 128 floats = 32 float4
    float4 a0 = t[(0 * MAXZV + i0) * 32 + c4];
    float4 a2 = t[(2 * MAXZV + i2) * 32 + c4];
    float4 a3 = t[(3 * MAXZV + i3) * 32 + c4];
    float4 a4 = t[(4 * MAXZV + i4) * 32 + c4];
    float4 a5 = t[(5 * MAXZV + i5) * 32 + c4];
    float4 a6 = t[(6 * MAXZV + i6) * 32 + c4];

    float4 s;
    s.x = a0.x + a2.x + a3.x + a4.x + a5.x + a6.x;
    s.y = a0.y + a2.y + a3.y + a4.y + a5.y + a6.y;
    s.z = a0.z + a2.z + a3.z + a4.z + a5.z + a6.z;
    s.w = a0.w + a2.w + a3.w + a4.w + a5.w + a6.w;

    ((float4*)out)[node * 32 + c4] = s;
}

extern "C" void kernel_launch(void* const* d_in, const int* in_sizes, int n_in,
                              void* d_out, int out_size, void* d_ws, size_t ws_size,
                              hipStream_t stream) {
    const int*   z             = (const int*)  d_in[0];
    const float* pos           = (const float*)d_in[1];
    const int*   edge_index    = (const int*)  d_in[2];
    const int*   edge_features = (const int*)  d_in[3];
    const float* center_pos    = (const float*)d_in[4];
    const float* z_tables      = (const float*)d_in[5];
    const float* ef_tables     = (const float*)d_in[6];
    const float* dV_table      = (const float*)d_in[7];

    float* out_emb1 = (float*)d_out;                                  // B*N*128
    float* out_ef   = out_emb1 + (size_t)BATCH * NNODE * ZHDIM;       // B*E*64

    float*  ws_A    = (float*)d_ws + WS_A_OFF_FLOATS;
    float4* ws_scal = (float4*)((float*)d_ws + WS_SCAL_OFF_FLOATS);

    // 1. combined (ef_tables-sum * dV_table) rows: 768 blocks
    combine_tables_kernel<<<AROWS * 16 / 256, 256, 0, stream>>>(ef_tables, dV_table, ws_A);

    // 2. per-edge scalars: 4096 blocks
    edge_scalar_kernel<<<NEDGES_TOT / 256, 256, 0, stream>>>(
        pos, edge_index, edge_features, center_pos, ws_scal);

    // 3. emb1 (independent): 8192 blocks
    emb1_kernel<<<BATCH * NNODE * 32 / 256, 256, 0, stream>>>(z, z_tables, out_emb1);

    // 4. ef expansion: 65536 blocks
    ef_expand_kernel<<<NEDGES_TOT * 16 / 256, 256, 0, stream>>>(
        ws_scal, ws_A, dV_table, out_ef);
}